// Round 6
// baseline (18.090 us; speedup 1.0000x reference)
//
#include <hip/hip_runtime.h>

#define TIMESTEPS 1000
#define BATCH 64
#define HH 256
#define WW 256
#define WAVES_PER_BLOCK 4
#define ROWS_PER_WAVE 2
#define NBLOCKS 2048                               // 8 blocks/CU x 256 CUs, exact
#define NWAVES (NBLOCKS * WAVES_PER_BLOCK)         // 8192 waves x 2 rows = 16384
#define HBINS 512                                  // bins per pass (1000 split in 2)
#define INVALID_T (1 << 30)

// Wave-private 512-bin histograms, two passes per row (bins [0,512) then
// [512,1000)), reusing the same buffer with a generation bump per pass.
// 4 KB LDS/wave -> 16 KB/block -> 8 blocks/CU uniform -> 32 waves/CU (HW max),
// double round-4's DS-stream concurrency WITHOUT the round-5 residency tail.
// Entry = (gen<<8)|y ; stale/empty entries decode negative under the current
// gen and clamp to 0 via v_max_i32 (no cndmask pair).
__global__ __launch_bounds__(256, 8) void holo_mse_kernel(
    const float* __restrict__ rec, const float* __restrict__ tgt,
    unsigned int* __restrict__ partials)
{
    __shared__ unsigned int hist[WAVES_PER_BLOCK][2][HBINS];  // 16 KB/block

    const int tid  = threadIdx.x;
    const int wave = tid >> 6;
    const int lane = tid & 63;

    unsigned int* hr = &hist[wave][0][0];
    unsigned int* ht = &hist[wave][1][0];

    // one-time init (gen 0 == invalid); contiguous b128 writes, uniform banks
    const uint4 z4 = make_uint4(0u, 0u, 0u, 0u);
    #pragma unroll
    for (int k = 0; k < 2; ++k) {
        *(uint4*)&hr[k * 256 + lane * 4] = z4;
        *(uint4*)&ht[k * 256 + lane * 4] = z4;
    }
    __builtin_amdgcn_wave_barrier();

    const int W    = blockIdx.x * WAVES_PER_BLOCK + wave;   // 0..8191
    const int row0 = W * ROWS_PER_WAVE;

    unsigned int acc = 0;
    unsigned int gen = 0;

    #pragma unroll
    for (int r = 0; r < ROWS_PER_WAVE; ++r) {
        const int row = row0 + r;

        const float4 vr4 = *(const float4*)&rec[(size_t)row * WW + lane * 4];
        const float4 vt4 = *(const float4*)&tgt[(size_t)row * WW + lane * 4];
        const float vr[4] = {vr4.x, vr4.y, vr4.z, vr4.w};
        const float vt[4] = {vt4.x, vt4.y, vt4.z, vt4.w};

        // compute bin indices ONCE per row, reuse across both passes
        int tr[4], ts[4];
        #pragma unroll
        for (int j = 0; j < 4; ++j) {
            int t = (int)(vr[j] * 1000.0f) - 1;     // trunc == astype(int32)
            if (t < 0) t += TIMESTEPS;              // python wrap: -1 -> 999
            tr[j] = (vr[j] != 0.0f && (unsigned)t < TIMESTEPS) ? t : INVALID_T;
            t = (int)(vt[j] * 1000.0f) - 1;
            if (t < 0) t += TIMESTEPS;
            ts[j] = (vt[j] != 0.0f && (unsigned)t < TIMESTEPS) ? t : INVALID_T;
        }

        #pragma unroll
        for (int p = 0; p < 2; ++p) {
            ++gen;                                   // 1..4, fits the tag
            const unsigned int genHi = gen << 8;
            const int base = p * HBINS;

            #pragma unroll
            for (int j = 0; j < 4; ++j) {
                const unsigned int y = (unsigned int)(lane * 4 + j);
                const int a = tr[j] - base;
                if ((unsigned)a < HBINS) atomicMax(&hr[a], genHi | y);
                const int b = ts[j] - base;
                if ((unsigned)b < HBINS) atomicMax(&ht[b], genHi | y);
            }
            __builtin_amdgcn_wave_barrier();  // reads after this pass's atomics
            // (DS ops within a wave complete in order; barrier is compiler-only)

            // scan 512 bins/image: contiguous b128 reads, all 32 banks uniform.
            // pass-2 bins 488..511 are never written -> decode 0 for both ->
            // d = 0, harmless.
            #pragma unroll
            for (int k = 0; k < 2; ++k) {
                const uint4 A = *(const uint4*)&hr[k * 256 + lane * 4];
                const uint4 B = *(const uint4*)&ht[k * 256 + lane * 4];
                const unsigned int Aa[4] = {A.x, A.y, A.z, A.w};
                const unsigned int Bb[4] = {B.x, B.y, B.z, B.w};
                #pragma unroll
                for (int j = 0; j < 4; ++j) {
                    int yr = (int)(Aa[j] - genHi); yr = yr > 0 ? yr : 0; // v_max_i32
                    int yt = (int)(Bb[j] - genHi); yt = yt > 0 ? yt : 0;
                    const int d = yr - yt;
                    acc += (unsigned int)(d * d);   // per-lane <= ~2.1M, exact
                }
            }
            __builtin_amdgcn_wave_barrier();  // next pass's atomics stay below
        }
    }

    // wave-64 shuffle reduce; one partial per wave, zero contention, no
    // __syncthreads anywhere in this kernel.
    #pragma unroll
    for (int off = 32; off > 0; off >>= 1) acc += __shfl_down(acc, off, 64);
    if (lane == 0) partials[W] = acc;
}

// Single block sums 8192 u32 partials exactly in u64 (32 KB, vectorized).
__global__ __launch_bounds__(256) void reduce_kernel(
    const unsigned int* __restrict__ partials, float* __restrict__ out)
{
    const int tid = threadIdx.x;
    const uint4* p4 = (const uint4*)partials;      // 2048 uint4 = 8 * 256
    unsigned long long s = 0;
    #pragma unroll
    for (int k = 0; k < 8; ++k) {
        const uint4 p = p4[k * 256 + tid];
        s += (unsigned long long)p.x + p.y + p.z + p.w;
    }

    #pragma unroll
    for (int off = 32; off > 0; off >>= 1) s += __shfl_down(s, off, 64);

    __shared__ unsigned long long wsum[4];
    const int wave = tid >> 6;
    if ((tid & 63) == 0) wsum[wave] = s;
    __syncthreads();

    if (tid == 0) {
        unsigned long long tot = wsum[0] + wsum[1] + wsum[2] + wsum[3];
        const double denom = (double)BATCH * (double)HH * (double)TIMESTEPS; // 16,384,000
        out[0] = (float)((double)tot / denom);
    }
}

extern "C" void kernel_launch(void* const* d_in, const int* in_sizes, int n_in,
                              void* d_out, int out_size, void* d_ws, size_t ws_size,
                              hipStream_t stream) {
    const float* rec = (const float*)d_in[0];
    const float* tgt = (const float*)d_in[1];
    float* out = (float*)d_out;
    unsigned int* partials = (unsigned int*)d_ws;   // 8192 * 4 B = 32 KB scratch

    holo_mse_kernel<<<NBLOCKS, 256, 0, stream>>>(rec, tgt, partials);
    reduce_kernel<<<1, 256, 0, stream>>>(partials, out);
}

// Round 7
// 12.764 us; speedup vs baseline: 1.4173x; 1.4173x over previous
//
#include <hip/hip_runtime.h>

#define TIMESTEPS 1000
#define BATCH 64
#define HH 256
#define WW 256
#define ROWS_PER_WAVE 4
#define WAVES_PER_BLOCK 4
#define NROWS (BATCH * HH)                                   // 16384
#define NBLOCKS (NROWS / (ROWS_PER_WAVE * WAVES_PER_BLOCK))  // 1024
#define HBINS 1024                                           // bins padded 1000 -> 1024

typedef short s16x2 __attribute__((ext_vector_type(2)));

// Round-4 structure (best measured: 14.65us): wave-private 1024-bin
// histograms, gen tags, 16 waves/CU. Rounds 5/6 proved the DS pipe is
// issue-saturated at 16 waves/CU (20 and 32 waves/CU both regressed), so
// this round keeps the schedule and trims VALU (packed i16 decode + sdot2)
// and partial-reduction overhead (per-block partials, 4KB reduce read).
__global__ __launch_bounds__(256) void holo_mse_kernel(
    const float* __restrict__ rec, const float* __restrict__ tgt,
    unsigned int* __restrict__ partials)
{
    __shared__ __align__(16) unsigned int hist[WAVES_PER_BLOCK][2][HBINS]; // 32 KB

    const int tid  = threadIdx.x;
    const int wave = tid >> 6;
    const int lane = tid & 63;

    unsigned int* hr = &hist[wave][0][0];
    unsigned int* ht = &hist[wave][1][0];

    // one-time init (gen 0 == invalid); contiguous b128 writes, uniform banks
    const uint4 z4 = make_uint4(0u, 0u, 0u, 0u);
    #pragma unroll
    for (int k = 0; k < 4; ++k) {
        *(uint4*)&hr[k * 256 + lane * 4] = z4;
        *(uint4*)&ht[k * 256 + lane * 4] = z4;
    }
    __builtin_amdgcn_wave_barrier();

    const int row0 = blockIdx.x * (ROWS_PER_WAVE * WAVES_PER_BLOCK) + wave * ROWS_PER_WAVE;

    unsigned int acc = 0;

    #pragma unroll
    for (int r = 0; r < ROWS_PER_WAVE; ++r) {
        const int row = row0 + r;
        const unsigned int genHi = (unsigned int)(r + 1) << 8;   // 1..4

        const float4 vr4 = *(const float4*)&rec[(size_t)row * WW + lane * 4];
        const float4 vt4 = *(const float4*)&tgt[(size_t)row * WW + lane * 4];
        const float vr[4] = {vr4.x, vr4.y, vr4.z, vr4.w};
        const float vt[4] = {vt4.x, vt4.y, vt4.z, vt4.w};

        #pragma unroll
        for (int j = 0; j < 4; ++j) {
            const unsigned int y = (unsigned int)(lane * 4 + j);
            if (vr[j] != 0.0f) {
                int t = (int)(vr[j] * 1000.0f) - 1;   // trunc == astype(int32)
                if (t < 0) t += TIMESTEPS;            // python wrap: -1 -> 999
                if ((unsigned)t < TIMESTEPS) atomicMax(&hr[t], genHi | y);
            }
            if (vt[j] != 0.0f) {
                int t = (int)(vt[j] * 1000.0f) - 1;
                if (t < 0) t += TIMESTEPS;
                if ((unsigned)t < TIMESTEPS) atomicMax(&ht[t], genHi | y);
            }
        }
        __builtin_amdgcn_wave_barrier();   // reads stay after this row's atomics
        // (DS ops within a wave complete in order; barrier is compiler-only)

        // scan: contiguous b128 reads (k*256 + lane*4 -> all 32 banks).
        // Decode 2 bins at a time: pack low16 of adjacent entries (v_perm),
        // packed sub gen / clamp 0 (v_pk_sub_i16 / v_pk_max_i16), then
        // d.d + acc in one v_dot2_i32_i16 where available.
        const unsigned int genPk = genHi | (genHi << 16);
        #pragma unroll
        for (int k = 0; k < 4; ++k) {
            const uint4 A = *(const uint4*)&hr[k * 256 + lane * 4];
            const uint4 B = *(const uint4*)&ht[k * 256 + lane * 4];
            const unsigned int Aw[4] = {A.x, A.y, A.z, A.w};
            const unsigned int Bw[4] = {B.x, B.y, B.z, B.w};
            #pragma unroll
            for (int h = 0; h < 2; ++h) {
                // pack [lo16(Aw[2h+1]) : lo16(Aw[2h])]
                unsigned int pa = __builtin_amdgcn_perm(Aw[2*h+1], Aw[2*h], 0x05040100u);
                unsigned int pb = __builtin_amdgcn_perm(Bw[2*h+1], Bw[2*h], 0x05040100u);
                s16x2 ya = (s16x2)(pa) - (s16x2)(genPk);
                s16x2 yb = (s16x2)(pb) - (s16x2)(genPk);
                ya = __builtin_elementwise_max(ya, (s16x2)0);  // stale/empty -> 0
                yb = __builtin_elementwise_max(yb, (s16x2)0);
                const s16x2 d = ya - yb;
#if __has_builtin(__builtin_amdgcn_sdot2)
                acc = (unsigned int)__builtin_amdgcn_sdot2(d, d, (int)acc, false);
#else
                acc += (unsigned int)((int)d.x * (int)d.x + (int)d.y * (int)d.y);
#endif
            }
        }
        __builtin_amdgcn_wave_barrier();   // next row's atomics stay below reads
    }

    // wave reduce, then one partial per BLOCK (1024 total; block sum <= 1.05e9,
    // fits u32). The single __syncthreads sits after all DS scatter work.
    #pragma unroll
    for (int off = 32; off > 0; off >>= 1) acc += __shfl_down(acc, off, 64);

    __shared__ unsigned int wsum[WAVES_PER_BLOCK];
    if (lane == 0) wsum[wave] = acc;
    __syncthreads();
    if (tid == 0)
        partials[blockIdx.x] = wsum[0] + wsum[1] + wsum[2] + wsum[3];
}

// Single block sums 1024 u32 partials exactly in u64 (4 KB read).
__global__ __launch_bounds__(256) void reduce_kernel(
    const unsigned int* __restrict__ partials, float* __restrict__ out)
{
    const int tid = threadIdx.x;
    const uint4 p = ((const uint4*)partials)[tid];          // 256 * 16B = 4 KB
    unsigned long long s = (unsigned long long)p.x + p.y + p.z + p.w;

    #pragma unroll
    for (int off = 32; off > 0; off >>= 1) s += __shfl_down(s, off, 64);

    __shared__ unsigned long long wsum[4];
    const int wave = tid >> 6;
    if ((tid & 63) == 0) wsum[wave] = s;
    __syncthreads();

    if (tid == 0) {
        unsigned long long tot = wsum[0] + wsum[1] + wsum[2] + wsum[3];
        const double denom = (double)BATCH * (double)HH * (double)TIMESTEPS; // 16,384,000
        out[0] = (float)((double)tot / denom);
    }
}

extern "C" void kernel_launch(void* const* d_in, const int* in_sizes, int n_in,
                              void* d_out, int out_size, void* d_ws, size_t ws_size,
                              hipStream_t stream) {
    const float* rec = (const float*)d_in[0];
    const float* tgt = (const float*)d_in[1];
    float* out = (float*)d_out;
    unsigned int* partials = (unsigned int*)d_ws;   // 1024 * 4 B = 4 KB scratch

    holo_mse_kernel<<<NBLOCKS, 256, 0, stream>>>(rec, tgt, partials);
    reduce_kernel<<<1, 256, 0, stream>>>(partials, out);
}